// Round 7
// baseline (106.901 us; speedup 1.0000x reference)
//
#include <hip/hip_runtime.h>
#include <hip/hip_bf16.h>
#include <cstddef>
#include <cstdint>

#define B_ 2
#define C_ 512
#define L_ 1024
#define NH_ 8
#define HD_ 64
#define OC_ 1536  // 3*C

typedef short short8 __attribute__((ext_vector_type(8)));
typedef short short4v __attribute__((ext_vector_type(4)));
typedef float f32x4 __attribute__((ext_vector_type(4)));
typedef __fp16 f16x4 __attribute__((ext_vector_type(4)));
typedef __fp16 f16x2 __attribute__((ext_vector_type(2)));

__device__ inline float bf_bits_to_f32(unsigned short u) {
  union { unsigned u32; float f; } c; c.u32 = ((unsigned)u) << 16; return c.f;
}
__device__ inline short f32_to_bf_bits(float f) {
  union { float f; unsigned u; } c; c.f = f;
  return (short)((c.u + 0x7FFFu + ((c.u >> 16) & 1u)) >> 16);
}

// ---------------------------------------------------------------------------
// K1: BN training-mode stats -> per-channel scale/shift (xn = x*s + t).
// ---------------------------------------------------------------------------
__global__ __launch_bounds__(256) void bn_stats_kernel(
    const float* __restrict__ x, const float* __restrict__ gamma,
    const float* __restrict__ beta, float* __restrict__ s_out,
    float* __restrict__ t_out)
{
  const int ch = blockIdx.x;
  const float* p0 = x + (size_t)ch * L_;
  const float* p1 = x + (size_t)(C_ + ch) * L_;
  float s1 = 0.f, s2 = 0.f;
  for (int i = threadIdx.x; i < L_; i += 256) {
    float v = p0[i]; s1 += v; s2 += v * v;
    v = p1[i];       s1 += v; s2 += v * v;
  }
  #pragma unroll
  for (int off = 32; off > 0; off >>= 1) {
    s1 += __shfl_down(s1, off);
    s2 += __shfl_down(s2, off);
  }
  __shared__ float r1[4], r2[4];
  const int wid = threadIdx.x >> 6, lane = threadIdx.x & 63;
  if (lane == 0) { r1[wid] = s1; r2[wid] = s2; }
  __syncthreads();
  if (threadIdx.x == 0) {
    const float S1 = r1[0] + r1[1] + r1[2] + r1[3];
    const float S2 = r2[0] + r2[1] + r2[2] + r2[3];
    const float invN = 1.f / (float)(B_ * L_);
    const float mean = S1 * invN;
    const float var  = S2 * invN - mean * mean;  // biased
    const float rstd = rsqrtf(var + 1e-5f);
    const float sc = gamma[ch] * rstd;
    s_out[ch] = sc;
    t_out[ch] = beta[ch] - mean * sc;
  }
}

// ---------------------------------------------------------------------------
// K2: fused MFMA GEMM. C[b] = A @ B[b] + bias (+res).
// A: MxK f32 row-major (converted to bf16 in A-staging).
// B: KxN natural layout (f32 or bf16), TRANSPOSED during staging into
//    Bs[n][k]; optional per-k affine (BN fold: v*s[k]+t[k]).
// 128x128 tile, BK=64, 4 waves, mfma_f32_16x16x32_bf16.
// Bs swizzle: slot ^ (n&7) ^ ((n&8)>>1)  (write ~2-way, read ~2-way: free).
// ---------------------------------------------------------------------------
template <bool B_BF16, bool AFFINE, bool OUT_BF16>
__global__ __launch_bounds__(256) void gemm_kernel(
    const float* __restrict__ A, const void* __restrict__ Bv,
    const float* __restrict__ bias, const float* __restrict__ saff,
    const float* __restrict__ taff, const float* __restrict__ res,
    void* __restrict__ Cv, int M, int N, int K,
    size_t sB, size_t sC, size_t sR)
{
  __shared__ short As[128 * 64];
  __shared__ short Bs[128 * 64];
  const int tid = threadIdx.x;
  const int l = tid & 63, w = tid >> 6;
  const int wr = w >> 1, wc = w & 1;
  const int n0 = blockIdx.x * 128, m0 = blockIdx.y * 128, bz = blockIdx.z;
  const float* Bf = (const float*)Bv + (size_t)bz * sB;
  const short* Bs16 = (const short*)Bv + (size_t)bz * sB;
  f32x4 acc[4][4] = {};

  const int nl = tid >> 1;         // B-stage: thread owns one n column
  const int kh = (tid & 1) * 32;   // and half the k range

  for (int k0 = 0; k0 < K; k0 += 64) {
    // ---- A stage: f32 -> bf16, row-major, XOR slot swizzle
    #pragma unroll
    for (int it = 0; it < 4; ++it) {
      const int i = it * 256 + tid;
      const int row = i >> 3, s = i & 7;
      const float* ap = A + (size_t)(m0 + row) * K + k0 + s * 8;
      const float4 a0 = *(const float4*)ap;
      const float4 a1 = *(const float4*)(ap + 4);
      short8 va;
      va[0] = f32_to_bf_bits(a0.x); va[1] = f32_to_bf_bits(a0.y);
      va[2] = f32_to_bf_bits(a0.z); va[3] = f32_to_bf_bits(a0.w);
      va[4] = f32_to_bf_bits(a1.x); va[5] = f32_to_bf_bits(a1.y);
      va[6] = f32_to_bf_bits(a1.z); va[7] = f32_to_bf_bits(a1.w);
      *(short8*)(As + row * 64 + (s ^ (row & 7)) * 8) = va;
    }
    // ---- B stage: transpose KxN -> Bs[n][k], convert (+affine)
    #pragma unroll
    for (int rq = 0; rq < 8; ++rq) {
      const int kb = kh + rq * 4;
      short4v wv;
      #pragma unroll
      for (int r = 0; r < 4; ++r) {
        const int kg = k0 + kb + r;
        if (B_BF16) {
          wv[r] = Bs16[(size_t)kg * N + n0 + nl];
        } else {
          float v = Bf[(size_t)kg * N + n0 + nl];
          if (AFFINE) v = fmaf(v, saff[kg], taff[kg]);
          wv[r] = f32_to_bf_bits(v);
        }
      }
      const int swz = (kb >> 3) ^ (nl & 7) ^ ((nl & 8) >> 1);
      *(short4v*)(Bs + nl * 64 + swz * 8 + (rq & 1) * 4) = wv;
    }
    __syncthreads();
    #pragma unroll
    for (int kk = 0; kk < 2; ++kk) {
      short8 af[4], bfg[4];
      const int sd = kk * 4 + (l >> 4);
      #pragma unroll
      for (int m = 0; m < 4; ++m) {
        const int ra = wr * 64 + m * 16 + (l & 15);
        af[m] = *(const short8*)(As + ra * 64 + (sd ^ (ra & 7)) * 8);
      }
      #pragma unroll
      for (int n = 0; n < 4; ++n) {
        const int rb = wc * 64 + n * 16 + (l & 15);
        bfg[n] = *(const short8*)(Bs + rb * 64 +
                                  (sd ^ (rb & 7) ^ ((rb & 8) >> 1)) * 8);
      }
      #pragma unroll
      for (int m = 0; m < 4; ++m)
        #pragma unroll
        for (int n = 0; n < 4; ++n)
          acc[m][n] = __builtin_amdgcn_mfma_f32_16x16x32_bf16(
              af[m], bfg[n], acc[m][n], 0, 0, 0);
    }
    __syncthreads();
  }

  // epilogue: D col = lane&15, row = 4*(lane>>4) + reg
  const int cl = l & 15, rg4 = (l >> 4) * 4;
  __hip_bfloat16* Cb = (__hip_bfloat16*)Cv + (size_t)bz * sC;
  float* Cf = (float*)Cv + (size_t)bz * sC;
  const float* Rp = res + (size_t)bz * sR;
  #pragma unroll
  for (int m = 0; m < 4; ++m) {
    #pragma unroll
    for (int reg = 0; reg < 4; ++reg) {
      const int gm = m0 + wr * 64 + m * 16 + rg4 + reg;
      const float bv = bias[gm];
      #pragma unroll
      for (int n = 0; n < 4; ++n) {
        const int gn = n0 + wc * 64 + n * 16 + cl;
        float v = acc[m][n][reg] + bv;
        if (OUT_BF16) {
          Cb[(size_t)gm * N + gn] = __hip_bfloat16_raw{(unsigned short)f32_to_bf_bits(v)};
        } else {
          v += Rp[(size_t)gm * N + gn];
          Cf[(size_t)gm * N + gn] = v;
        }
      }
    }
  }
}

// ---------------------------------------------------------------------------
// K3: MFMA attention v3 — transpose-free P path.
// Grid (tq=8, d=64, b=2) = 1024 blocks, 256 thr = 4 waves; wave owns 32 rows.
// K[f][g] (bf16) and V[g][f] (f16, slot-swizzled) staged ONCE -> 1 barrier.
// Per 16-f tile ft, per 16-t tile tt:
//   S = mfma_f32_16x16x32_bf16(K-frag, Q^T-frag)   (g padded to 32)
//   lane holds S[f=4*lh+reg][t=ll] -> exp2 -> cvt_pkrtz -> f16x4
//   == EXACTLY the B-fragment layout of mfma_f32_16x16x16_f16 (k=4*lh+j)
//   O^T[g][t] += mfma_f32_16x16x16_f16(V-frag (row8=ones -> rowsum), P)
// No P LDS round-trip, no inner-loop barriers, denominator free via ones row.
// ---------------------------------------------------------------------------
__global__ __launch_bounds__(256, 4) void attn_kernel(
    const __hip_bfloat16* __restrict__ qkv, __hip_bfloat16* __restrict__ h)
{
  __shared__ short Klds[1024 * 8];    // [f][g] bf16, 16 KB
  __shared__ __fp16 Vlds[8 * 1024];   // [g][f] f16, swizzled, 16 KB

  const int tq = blockIdx.x, d = blockIdx.y, b = blockIdx.z;
  const int tid = threadIdx.x;
  const int w = tid >> 6, l = tid & 63;
  const int lh = l >> 4, ll = l & 15;
  const int t0 = tq * 128 + w * 32;
  const short* base = (const short*)qkv + (size_t)b * OC_ * L_;
  short* VldsS = (short*)Vlds;

  // ---- stage K[f][g] (coalesced along f)
  #pragma unroll
  for (int it = 0; it < 4; ++it) {
    const int f = it * 256 + tid;
    short8 kv;
    #pragma unroll
    for (int g = 0; g < 8; ++g)
      kv[g] = base[(size_t)((8 + g) * HD_ + d) * L_ + f];
    *(short8*)(Klds + f * 8) = kv;
  }
  // ---- stage V[g][f] as f16, slot-swizzled: slot' = (s&15)^g within 16-win
  #pragma unroll
  for (int it = 0; it < 4; ++it) {
    const int i = it * 256 + tid;
    const int g = i >> 7, fs = i & 127;
    const short8 v = *(const short8*)(
        base + (size_t)((16 + g) * HD_ + d) * L_ + fs * 8);
    unsigned u[4];
    #pragma unroll
    for (int e = 0; e < 4; ++e) {
      const f16x2 p = __builtin_amdgcn_cvt_pkrtz(
          bf_bits_to_f32((unsigned short)v[2 * e]),
          bf_bits_to_f32((unsigned short)v[2 * e + 1]));
      u[e] = __builtin_bit_cast(unsigned, p);
    }
    uint4 uu; uu.x = u[0]; uu.y = u[1]; uu.z = u[2]; uu.w = u[3];
    *(uint4*)(VldsS + g * 1024 + ((fs & ~15) + ((fs & 15) ^ g)) * 8) = uu;
  }

  // ---- Q B-fragments (lanes l<16): B[k=g][t], scale*log2e folded in
  short8 bQ[2] = {};
  if (l < 16) {
    #pragma unroll
    for (int tt = 0; tt < 2; ++tt) {
      const int t = t0 + tt * 16 + ll;
      short8 qv;
      #pragma unroll
      for (int g = 0; g < 8; ++g) {
        const float v = bf_bits_to_f32(
            (unsigned short)base[(size_t)(g * HD_ + d) * L_ + t]);
        qv[g] = f32_to_bf_bits(v * 0.29448889f);  // 24^-0.5 * log2(e)
      }
      bQ[tt] = qv;
    }
  }

  __syncthreads();  // K/V staged; no further barriers

  f16x4 vone, vzero;
  vone[0] = (__fp16)1.f; vone[1] = (__fp16)1.f;
  vone[2] = (__fp16)1.f; vone[3] = (__fp16)1.f;
  vzero[0] = (__fp16)0.f; vzero[1] = (__fp16)0.f;
  vzero[2] = (__fp16)0.f; vzero[3] = (__fp16)0.f;
  f32x4 accO[2] = {};

  for (int c = 0; c < 8; ++c) {
    // batch this chunk's K fragments (A[f][g], lanes l<16 real)
    short8 ak[8];
    #pragma unroll
    for (int ft = 0; ft < 8; ++ft) {
      short8 kv = {};
      if (l < 16)
        kv = *(const short8*)(Klds + (size_t)(c * 128 + ft * 16 + ll) * 8);
      ak[ft] = kv;
    }
    // batch V fragments (A[g][f_local=4*lh+j]; row 8 = ones for rowsum)
    f16x4 av[8];
    #pragma unroll
    for (int ft = 0; ft < 8; ++ft) {
      const int s16 = ft * 2 + (lh >> 1);
      const f16x4 raw = *(const f16x4*)(
          Vlds + (l & 7) * 1024 + c * 128 + ((s16 ^ (l & 7)) * 8) + (lh & 1) * 4);
      av[ft] = (ll < 8) ? raw : ((ll == 8) ? vone : vzero);
    }
    #pragma unroll
    for (int ft = 0; ft < 8; ++ft) {
      #pragma unroll
      for (int tt = 0; tt < 2; ++tt) {
        const f32x4 s = __builtin_amdgcn_mfma_f32_16x16x32_bf16(
            ak[ft], bQ[tt], (f32x4){0.f, 0.f, 0.f, 0.f}, 0, 0, 0);
        const f16x2 p0 = __builtin_amdgcn_cvt_pkrtz(exp2f(s[0]), exp2f(s[1]));
        const f16x2 p1 = __builtin_amdgcn_cvt_pkrtz(exp2f(s[2]), exp2f(s[3]));
        f16x4 bP;
        bP[0] = p0[0]; bP[1] = p0[1]; bP[2] = p1[0]; bP[3] = p1[1];
        accO[tt] = __builtin_amdgcn_mfma_f32_16x16x16f16(av[ft], bP, accO[tt], 0, 0, 0);
      }
    }
  }

  // ---- epilogue: D row 8 (lane 32+ll, reg 0) = softmax denominator
  short* hb = (short*)h + (size_t)b * C_ * L_;
  #pragma unroll
  for (int nt = 0; nt < 2; ++nt) {
    const float sum = __shfl(accO[nt][0], 32 + ll);
    const float inv = 1.f / sum;
    if (lh < 2) {
      const int t = t0 + nt * 16 + ll;
      #pragma unroll
      for (int reg = 0; reg < 4; ++reg) {
        const int g = lh * 4 + reg;
        hb[(size_t)(g * HD_ + d) * L_ + t] = f32_to_bf_bits(accO[nt][reg] * inv);
      }
    }
  }
}

// ---------------------------------------------------------------------------
extern "C" void kernel_launch(void* const* d_in, const int* in_sizes, int n_in,
                              void* d_out, int out_size, void* d_ws, size_t ws_size,
                              hipStream_t stream) {
  (void)in_sizes; (void)n_in; (void)out_size; (void)ws_size;
  const float* x      = (const float*)d_in[0];
  const float* gamma  = (const float*)d_in[1];
  const float* beta   = (const float*)d_in[2];
  const float* w_qkv  = (const float*)d_in[3];
  const float* b_qkv  = (const float*)d_in[4];
  const float* w_proj = (const float*)d_in[5];
  const float* b_proj = (const float*)d_in[6];
  float* out = (float*)d_out;
  char* wsb = (char*)d_ws;

  // workspace: ~8 MB
  float* s_buf = (float*)(wsb + 0);
  float* t_buf = (float*)(wsb + 2048);
  __hip_bfloat16* qkv = (__hip_bfloat16*)(wsb + 4096);                // 2x1536x1024
  __hip_bfloat16* hb  = (__hip_bfloat16*)(wsb + 4096 + 6291456);      // 2x512x1024

  hipLaunchKernelGGL(bn_stats_kernel, dim3(C_), dim3(256), 0, stream,
                     x, gamma, beta, s_buf, t_buf);
  // qkv = W_qkv @ (x*s + t) + b_qkv   (BN folded into B-staging)
  hipLaunchKernelGGL((gemm_kernel<false, true, true>),
                     dim3(L_ / 128, OC_ / 128, B_), dim3(256), 0, stream,
                     w_qkv, (const void*)x, b_qkv, s_buf, t_buf,
                     (const float*)nullptr, (void*)qkv,
                     OC_, L_, C_, (size_t)C_ * L_, (size_t)OC_ * L_, (size_t)0);
  hipLaunchKernelGGL(attn_kernel, dim3(8, HD_, B_), dim3(256), 0, stream,
                     qkv, hb);
  // out = W_proj @ h + b_proj + x
  hipLaunchKernelGGL((gemm_kernel<true, false, false>),
                     dim3(L_ / 128, C_ / 128, B_), dim3(256), 0, stream,
                     w_proj, (const void*)hb, b_proj,
                     (const float*)nullptr, (const float*)nullptr, x, (void*)out,
                     C_, L_, C_, (size_t)C_ * L_, (size_t)C_ * L_, (size_t)C_ * L_);
}

// Round 8
// 74.176 us; speedup vs baseline: 1.4412x; 1.4412x over previous
//
#include <hip/hip_runtime.h>
#include <hip/hip_bf16.h>
#include <cstddef>
#include <cstdint>

#define B_ 2
#define C_ 512
#define L_ 1024
#define NH_ 8
#define HD_ 64
#define OC_ 1536  // 3*C

typedef short short8 __attribute__((ext_vector_type(8)));
typedef short short4v __attribute__((ext_vector_type(4)));
typedef float f32x4 __attribute__((ext_vector_type(4)));
typedef __fp16 f16x4 __attribute__((ext_vector_type(4)));
typedef __fp16 f16x2 __attribute__((ext_vector_type(2)));

__device__ inline float bf_bits_to_f32(unsigned short u) {
  union { unsigned u32; float f; } c; c.u32 = ((unsigned)u) << 16; return c.f;
}
__device__ inline short f32_to_bf_bits(float f) {
  union { float f; unsigned u; } c; c.f = f;
  return (short)((c.u + 0x7FFFu + ((c.u >> 16) & 1u)) >> 16);
}

// ---------------------------------------------------------------------------
// K1 prep: blocks 0-511: BN stats -> s,t per channel.
//          blocks 512-703: w_qkv f32 -> bf16 (wq16).
//          blocks 704-767: w_proj permuted cols -> bf16 (wpp[o][d*8+g]).
// ---------------------------------------------------------------------------
__global__ __launch_bounds__(256) void prep_kernel(
    const float* __restrict__ x, const float* __restrict__ gamma,
    const float* __restrict__ beta, const float* __restrict__ w_qkv,
    const float* __restrict__ w_proj,
    float* __restrict__ s_out, float* __restrict__ t_out,
    short* __restrict__ wq16, short* __restrict__ wpp16)
{
  const int bid = blockIdx.x;
  const int tid = threadIdx.x;
  if (bid < 512) {
    const int ch = bid;
    const float* p0 = x + (size_t)ch * L_;
    const float* p1 = x + (size_t)(C_ + ch) * L_;
    float s1 = 0.f, s2 = 0.f;
    for (int i = tid; i < L_; i += 256) {
      float v = p0[i]; s1 += v; s2 += v * v;
      v = p1[i];       s1 += v; s2 += v * v;
    }
    #pragma unroll
    for (int off = 32; off > 0; off >>= 1) {
      s1 += __shfl_down(s1, off);
      s2 += __shfl_down(s2, off);
    }
    __shared__ float r1[4], r2[4];
    const int wid = tid >> 6, lane = tid & 63;
    if (lane == 0) { r1[wid] = s1; r2[wid] = s2; }
    __syncthreads();
    if (tid == 0) {
      const float S1 = r1[0] + r1[1] + r1[2] + r1[3];
      const float S2 = r2[0] + r2[1] + r2[2] + r2[3];
      const float invN = 1.f / (float)(B_ * L_);
      const float mean = S1 * invN;
      const float var  = S2 * invN - mean * mean;  // biased
      const float rstd = rsqrtf(var + 1e-5f);
      const float sc = gamma[ch] * rstd;
      s_out[ch] = sc;
      t_out[ch] = beta[ch] - mean * sc;
    }
  } else if (bid < 704) {
    // w_qkv convert: 192 blocks x 4096 elems
    const int base = (bid - 512) * 4096 + tid * 16;
    #pragma unroll
    for (int it = 0; it < 2; ++it) {
      const float4 a0 = *(const float4*)(w_qkv + base + it * 8);
      const float4 a1 = *(const float4*)(w_qkv + base + it * 8 + 4);
      short8 v;
      v[0] = f32_to_bf_bits(a0.x); v[1] = f32_to_bf_bits(a0.y);
      v[2] = f32_to_bf_bits(a0.z); v[3] = f32_to_bf_bits(a0.w);
      v[4] = f32_to_bf_bits(a1.x); v[5] = f32_to_bf_bits(a1.y);
      v[6] = f32_to_bf_bits(a1.z); v[7] = f32_to_bf_bits(a1.w);
      *(short8*)(wq16 + base + it * 8) = v;
    }
  } else {
    // w_proj permute+convert: 64 blocks x 4096; wpp[o][c'] = w[o][(c'&7)*64+(c'>>3)]
    #pragma unroll
    for (int grp = 0; grp < 4; ++grp) {
      const int idx = (bid - 704) * 4096 + tid * 16 + grp * 4;
      const int o = idx >> 9, cp = idx & 511;
      short4v v;
      #pragma unroll
      for (int j = 0; j < 4; ++j) {
        const int c = ((cp + j) & 7) * 64 + ((cp + j) >> 3);
        v[j] = f32_to_bf_bits(w_proj[(size_t)o * C_ + c]);
      }
      *(short4v*)(wpp16 + (size_t)o * C_ + cp) = v;
    }
  }
}

// ---------------------------------------------------------------------------
// K2: xT[b][t][c] = bf16(x[b][c][t]*s[c] + t[c])  (BN folded into transpose)
// 64x64 LDS tiles; coalesced reads along t, coalesced writes along c.
// ---------------------------------------------------------------------------
__global__ __launch_bounds__(256) void xt_kernel(
    const float* __restrict__ x, const float* __restrict__ s,
    const float* __restrict__ t, short* __restrict__ xT)
{
  __shared__ float T[64][65];
  const int t0 = blockIdx.x * 64, c0 = blockIdx.y * 64, b = blockIdx.z;
  const int tid = threadIdx.x;
  const float* xp = x + (size_t)b * C_ * L_;
  #pragma unroll
  for (int it = 0; it < 16; ++it) {
    const int idx = it * 256 + tid;
    const int rr = idx >> 6, cc = idx & 63;  // rr = c-local, cc = t-local
    T[rr][cc] = fmaf(xp[(size_t)(c0 + rr) * L_ + t0 + cc], s[c0 + rr], t[c0 + rr]);
  }
  __syncthreads();
  #pragma unroll
  for (int it = 0; it < 16; ++it) {
    const int idx = it * 256 + tid;
    const int cc = idx >> 6, rr = idx & 63;
    xT[((size_t)b * L_ + t0 + cc) * C_ + c0 + rr] = f32_to_bf_bits(T[rr][cc]);
  }
}

// ---------------------------------------------------------------------------
// K3: bf16 MFMA GEMM, both operands row-major shared-K (B transposed form).
// C[m][n] = sum_k A[m][k] * B[n][k] + bias (+res for f32 out).
// 4 waves (2x2), wave tile (MR*16)x(NR*16); BM=MR*32, BN=NR*32, BK=64.
// XOR slot-swizzle (slot ^ (row&7)) on LDS write+read: conflict-free-ish.
// ---------------------------------------------------------------------------
template <int MR, int NR, bool OUT_BF16>
__global__ __launch_bounds__(256) void gemm_bt16_kernel(
    const short* __restrict__ A, const short* __restrict__ B,
    const float* __restrict__ bias, const float* __restrict__ res,
    void* __restrict__ Cv, int M, int N, int K,
    size_t sB, size_t sC, size_t sR)
{
  constexpr int BM = MR * 32, BN = NR * 32;
  __shared__ short As[BM * 64];
  __shared__ short Bs[BN * 64];
  const int tid = threadIdx.x;
  const int l = tid & 63, w = tid >> 6;
  const int wr = w >> 1, wc = w & 1;
  const int ll = l & 15;
  const int n0 = blockIdx.x * BN, m0 = blockIdx.y * BM, bz = blockIdx.z;
  const short* Bg = B + (size_t)bz * sB;
  f32x4 acc[MR][NR] = {};

  for (int k0 = 0; k0 < K; k0 += 64) {
    #pragma unroll
    for (int it = 0; it < BM / 32; ++it) {
      const int i = it * 256 + tid;
      const int row = i >> 3, s = i & 7;
      const short8 va = *(const short8*)(A + (size_t)(m0 + row) * K + k0 + s * 8);
      *(short8*)(As + row * 64 + (s ^ (row & 7)) * 8) = va;
    }
    #pragma unroll
    for (int it = 0; it < BN / 32; ++it) {
      const int i = it * 256 + tid;
      const int row = i >> 3, s = i & 7;
      const short8 vb = *(const short8*)(Bg + (size_t)(n0 + row) * K + k0 + s * 8);
      *(short8*)(Bs + row * 64 + (s ^ (row & 7)) * 8) = vb;
    }
    __syncthreads();
    #pragma unroll
    for (int kk = 0; kk < 2; ++kk) {
      short8 af[MR], bfg[NR];
      const int sd = kk * 4 + (l >> 4);
      #pragma unroll
      for (int m = 0; m < MR; ++m) {
        const int ra = wr * MR * 16 + m * 16 + ll;
        af[m] = *(const short8*)(As + ra * 64 + (sd ^ (ra & 7)) * 8);
      }
      #pragma unroll
      for (int n = 0; n < NR; ++n) {
        const int rb = wc * NR * 16 + n * 16 + ll;
        bfg[n] = *(const short8*)(Bs + rb * 64 + (sd ^ (rb & 7)) * 8);
      }
      #pragma unroll
      for (int m = 0; m < MR; ++m)
        #pragma unroll
        for (int n = 0; n < NR; ++n)
          acc[m][n] = __builtin_amdgcn_mfma_f32_16x16x32_bf16(
              af[m], bfg[n], acc[m][n], 0, 0, 0);
    }
    __syncthreads();
  }

  // epilogue: D col = lane&15, row = 4*(lane>>4) + reg
  const int rg4 = (l >> 4) * 4;
  __hip_bfloat16* Cb = (__hip_bfloat16*)Cv + (size_t)bz * sC;
  float* Cf = (float*)Cv + (size_t)bz * sC;
  const float* Rp = res + (size_t)bz * sR;
  #pragma unroll
  for (int m = 0; m < MR; ++m) {
    #pragma unroll
    for (int reg = 0; reg < 4; ++reg) {
      const int gm = m0 + wr * MR * 16 + m * 16 + rg4 + reg;
      const float bv = bias[gm];
      #pragma unroll
      for (int n = 0; n < NR; ++n) {
        const int gn = n0 + wc * NR * 16 + n * 16 + ll;
        float v = acc[m][n][reg] + bv;
        if (OUT_BF16) {
          Cb[(size_t)gm * N + gn] = __hip_bfloat16_raw{(unsigned short)f32_to_bf_bits(v)};
        } else {
          v += Rp[(size_t)gm * N + gn];
          Cf[(size_t)gm * N + gn] = v;
        }
      }
    }
  }
}

// ---------------------------------------------------------------------------
// K4: MFMA attention (round-7 core, unchanged math). Output now hT[t][d*8+g]
// via LDS re-stage (16B/row coalesced-ish stores), killing the h transpose.
// ---------------------------------------------------------------------------
__global__ __launch_bounds__(256, 4) void attn_kernel(
    const __hip_bfloat16* __restrict__ qkv, short* __restrict__ hT)
{
  __shared__ short Klds[1024 * 8];    // [f][g] bf16, 16 KB (reused for O out)
  __shared__ __fp16 Vlds[8 * 1024];   // [g][f] f16, swizzled, 16 KB

  const int tq = blockIdx.x, d = blockIdx.y, b = blockIdx.z;
  const int tid = threadIdx.x;
  const int w = tid >> 6, l = tid & 63;
  const int lh = l >> 4, ll = l & 15;
  const int t0 = tq * 128 + w * 32;
  const short* base = (const short*)qkv + (size_t)b * OC_ * L_;
  short* VldsS = (short*)Vlds;

  // ---- stage K[f][g] (coalesced along f)
  #pragma unroll
  for (int it = 0; it < 4; ++it) {
    const int f = it * 256 + tid;
    short8 kv;
    #pragma unroll
    for (int g = 0; g < 8; ++g)
      kv[g] = base[(size_t)((8 + g) * HD_ + d) * L_ + f];
    *(short8*)(Klds + f * 8) = kv;
  }
  // ---- stage V[g][f] as f16, slot-swizzled within 16-slot windows
  #pragma unroll
  for (int it = 0; it < 4; ++it) {
    const int i = it * 256 + tid;
    const int g = i >> 7, fs = i & 127;
    const short8 v = *(const short8*)(
        base + (size_t)((16 + g) * HD_ + d) * L_ + fs * 8);
    unsigned u[4];
    #pragma unroll
    for (int e = 0; e < 4; ++e) {
      const f16x2 p = __builtin_amdgcn_cvt_pkrtz(
          bf_bits_to_f32((unsigned short)v[2 * e]),
          bf_bits_to_f32((unsigned short)v[2 * e + 1]));
      u[e] = __builtin_bit_cast(unsigned, p);
    }
    uint4 uu; uu.x = u[0]; uu.y = u[1]; uu.z = u[2]; uu.w = u[3];
    *(uint4*)(VldsS + g * 1024 + ((fs & ~15) + ((fs & 15) ^ g)) * 8) = uu;
  }

  // ---- Q B-fragments (lanes l<16): B[k=g][t], scale*log2e folded in
  short8 bQ[2] = {};
  if (l < 16) {
    #pragma unroll
    for (int tt = 0; tt < 2; ++tt) {
      const int t = t0 + tt * 16 + ll;
      short8 qv;
      #pragma unroll
      for (int g = 0; g < 8; ++g) {
        const float v = bf_bits_to_f32(
            (unsigned short)base[(size_t)(g * HD_ + d) * L_ + t]);
        qv[g] = f32_to_bf_bits(v * 0.29448889f);  // 24^-0.5 * log2(e)
      }
      bQ[tt] = qv;
    }
  }

  __syncthreads();  // K/V staged

  f16x4 vone, vzero;
  vone[0] = (__fp16)1.f; vone[1] = (__fp16)1.f;
  vone[2] = (__fp16)1.f; vone[3] = (__fp16)1.f;
  vzero[0] = (__fp16)0.f; vzero[1] = (__fp16)0.f;
  vzero[2] = (__fp16)0.f; vzero[3] = (__fp16)0.f;
  f32x4 accO[2] = {};

  for (int c = 0; c < 8; ++c) {
    short8 ak[8];
    #pragma unroll
    for (int ft = 0; ft < 8; ++ft) {
      short8 kv = {};
      if (l < 16)
        kv = *(const short8*)(Klds + (size_t)(c * 128 + ft * 16 + ll) * 8);
      ak[ft] = kv;
    }
    f16x4 av[8];
    #pragma unroll
    for (int ft = 0; ft < 8; ++ft) {
      const int s16 = ft * 2 + (lh >> 1);
      const f16x4 raw = *(const f16x4*)(
          Vlds + (l & 7) * 1024 + c * 128 + ((s16 ^ (l & 7)) * 8) + (lh & 1) * 4);
      av[ft] = (ll < 8) ? raw : ((ll == 8) ? vone : vzero);
    }
    #pragma unroll
    for (int ft = 0; ft < 8; ++ft) {
      #pragma unroll
      for (int tt = 0; tt < 2; ++tt) {
        const f32x4 s = __builtin_amdgcn_mfma_f32_16x16x32_bf16(
            ak[ft], bQ[tt], (f32x4){0.f, 0.f, 0.f, 0.f}, 0, 0, 0);
        const f16x2 p0 = __builtin_amdgcn_cvt_pkrtz(exp2f(s[0]), exp2f(s[1]));
        const f16x2 p1 = __builtin_amdgcn_cvt_pkrtz(exp2f(s[2]), exp2f(s[3]));
        f16x4 bP;
        bP[0] = p0[0]; bP[1] = p0[1]; bP[2] = p1[0]; bP[3] = p1[1];
        accO[tt] = __builtin_amdgcn_mfma_f32_16x16x16f16(av[ft], bP, accO[tt], 0, 0, 0);
      }
    }
  }

  // ---- epilogue: D row 8 (lane 32+ll, reg 0) = denominator; route O via LDS
  __syncthreads();                 // all waves done with Klds
  short* Olds = Klds;              // [128][8]
  #pragma unroll
  for (int nt = 0; nt < 2; ++nt) {
    const float sum = __shfl(accO[nt][0], 32 + ll);
    const float inv = 1.f / sum;
    if (lh < 2) {
      const int tl = w * 32 + nt * 16 + ll;
      #pragma unroll
      for (int reg = 0; reg < 4; ++reg)
        Olds[tl * 8 + lh * 4 + reg] = f32_to_bf_bits(accO[nt][reg] * inv);
    }
  }
  __syncthreads();
  if (tid < 128) {
    const short8 ov = *(const short8*)(Olds + tid * 8);
    *(short8*)(hT + ((size_t)b * L_ + tq * 128 + tid) * C_ + d * 8) = ov;
  }
}

// ---------------------------------------------------------------------------
extern "C" void kernel_launch(void* const* d_in, const int* in_sizes, int n_in,
                              void* d_out, int out_size, void* d_ws, size_t ws_size,
                              hipStream_t stream) {
  (void)in_sizes; (void)n_in; (void)out_size; (void)ws_size;
  const float* x      = (const float*)d_in[0];
  const float* gamma  = (const float*)d_in[1];
  const float* beta   = (const float*)d_in[2];
  const float* w_qkv  = (const float*)d_in[3];
  const float* b_qkv  = (const float*)d_in[4];
  const float* w_proj = (const float*)d_in[5];
  const float* b_proj = (const float*)d_in[6];
  float* out = (float*)d_out;
  char* wsb = (char*)d_ws;

  // workspace layout (bytes), ~12 MB
  float* s_buf = (float*)(wsb + 0);                         // 2 KB
  float* t_buf = (float*)(wsb + 2048);                      // 2 KB
  short* wq16  = (short*)(wsb + 4096);                      // 1.5 MB
  short* wpp16 = (short*)(wsb + 4096 + 1572864);            // 0.5 MB
  short* xT    = (short*)(wsb + 4096 + 2097152);            // 2 MB
  short* qkv   = (short*)(wsb + 4096 + 4194304);            // 6 MB
  short* hT    = (short*)(wsb + 4096 + 10485760);           // 2 MB

  hipLaunchKernelGGL(prep_kernel, dim3(768), dim3(256), 0, stream,
                     x, gamma, beta, w_qkv, w_proj, s_buf, t_buf, wq16, wpp16);
  hipLaunchKernelGGL(xt_kernel, dim3(L_ / 64, C_ / 64, B_), dim3(256), 0, stream,
                     x, s_buf, t_buf, xT);
  // qkv[o][t] = wq16 @ xn + b_qkv
  hipLaunchKernelGGL((gemm_bt16_kernel<4, 4, true>),
                     dim3(L_ / 128, OC_ / 128, B_), dim3(256), 0, stream,
                     wq16, xT, b_qkv, (const float*)nullptr, (void*)qkv,
                     OC_, L_, C_, (size_t)L_ * C_, (size_t)OC_ * L_, (size_t)0);
  hipLaunchKernelGGL(attn_kernel, dim3(8, HD_, B_), dim3(256), 0, stream,
                     (const __hip_bfloat16*)qkv, hT);
  // out = wpp @ hT^T + b_proj + x   (channel-permuted weights match hT layout)
  hipLaunchKernelGGL((gemm_bt16_kernel<2, 2, false>),
                     dim3(L_ / 64, C_ / 64, B_), dim3(256), 0, stream,
                     wpp16, hT, b_proj, x, (void*)out,
                     C_, L_, C_, (size_t)L_ * C_, (size_t)C_ * L_, (size_t)C_ * L_);
}

// Round 9
// 53.519 us; speedup vs baseline: 1.9974x; 1.3860x over previous
//
#include <hip/hip_runtime.h>
#include <hip/hip_bf16.h>
#include <cstddef>
#include <cstdint>

#define B_ 2
#define C_ 512
#define L_ 1024
#define NH_ 8
#define HD_ 64
#define OC_ 1536  // 3*C

typedef short short8 __attribute__((ext_vector_type(8)));
typedef short short4v __attribute__((ext_vector_type(4)));
typedef float f32x4 __attribute__((ext_vector_type(4)));
typedef __fp16 f16x4 __attribute__((ext_vector_type(4)));
typedef __fp16 f16x2 __attribute__((ext_vector_type(2)));

// Fast 2^x: raw v_exp_f32 (1ulp) -- the OCML/backend exp2 adds an IEEE
// denormal-scaling sequence (~6-8 VALU ops) that dominated round-8's attn.
#if defined(__has_builtin)
#if __has_builtin(__builtin_amdgcn_exp2f)
#define FEXP2(x) __builtin_amdgcn_exp2f(x)
#endif
#endif
#ifndef FEXP2
#define FEXP2(x) exp2f(x)
#endif

__device__ inline float bf_bits_to_f32(unsigned short u) {
  union { unsigned u32; float f; } c; c.u32 = ((unsigned)u) << 16; return c.f;
}
__device__ inline short f32_to_bf_bits(float f) {
  union { float f; unsigned u; } c; c.f = f;
  return (short)((c.u + 0x7FFFu + ((c.u >> 16) & 1u)) >> 16);
}

// ---------------------------------------------------------------------------
// K1 prep: blocks 0-511: BN stats -> s,t per channel.
//          blocks 512-703: w_qkv f32 -> bf16 (wq16).
//          blocks 704-767: w_proj permuted cols -> bf16 (wpp[o][d*8+g]).
// ---------------------------------------------------------------------------
__global__ __launch_bounds__(256) void prep_kernel(
    const float* __restrict__ x, const float* __restrict__ gamma,
    const float* __restrict__ beta, const float* __restrict__ w_qkv,
    const float* __restrict__ w_proj,
    float* __restrict__ s_out, float* __restrict__ t_out,
    short* __restrict__ wq16, short* __restrict__ wpp16)
{
  const int bid = blockIdx.x;
  const int tid = threadIdx.x;
  if (bid < 512) {
    const int ch = bid;
    const float* p0 = x + (size_t)ch * L_;
    const float* p1 = x + (size_t)(C_ + ch) * L_;
    float s1 = 0.f, s2 = 0.f;
    for (int i = tid; i < L_; i += 256) {
      float v = p0[i]; s1 += v; s2 += v * v;
      v = p1[i];       s1 += v; s2 += v * v;
    }
    #pragma unroll
    for (int off = 32; off > 0; off >>= 1) {
      s1 += __shfl_down(s1, off);
      s2 += __shfl_down(s2, off);
    }
    __shared__ float r1[4], r2[4];
    const int wid = tid >> 6, lane = tid & 63;
    if (lane == 0) { r1[wid] = s1; r2[wid] = s2; }
    __syncthreads();
    if (tid == 0) {
      const float S1 = r1[0] + r1[1] + r1[2] + r1[3];
      const float S2 = r2[0] + r2[1] + r2[2] + r2[3];
      const float invN = 1.f / (float)(B_ * L_);
      const float mean = S1 * invN;
      const float var  = S2 * invN - mean * mean;  // biased
      const float rstd = rsqrtf(var + 1e-5f);
      const float sc = gamma[ch] * rstd;
      s_out[ch] = sc;
      t_out[ch] = beta[ch] - mean * sc;
    }
  } else if (bid < 704) {
    // w_qkv convert: 192 blocks x 4096 elems
    const int base = (bid - 512) * 4096 + tid * 16;
    #pragma unroll
    for (int it = 0; it < 2; ++it) {
      const float4 a0 = *(const float4*)(w_qkv + base + it * 8);
      const float4 a1 = *(const float4*)(w_qkv + base + it * 8 + 4);
      short8 v;
      v[0] = f32_to_bf_bits(a0.x); v[1] = f32_to_bf_bits(a0.y);
      v[2] = f32_to_bf_bits(a0.z); v[3] = f32_to_bf_bits(a0.w);
      v[4] = f32_to_bf_bits(a1.x); v[5] = f32_to_bf_bits(a1.y);
      v[6] = f32_to_bf_bits(a1.z); v[7] = f32_to_bf_bits(a1.w);
      *(short8*)(wq16 + base + it * 8) = v;
    }
  } else {
    // w_proj permute+convert: wpp[o][c'] = w[o][(c'&7)*64+(c'>>3)]
    #pragma unroll
    for (int grp = 0; grp < 4; ++grp) {
      const int idx = (bid - 704) * 4096 + tid * 16 + grp * 4;
      const int o = idx >> 9, cp = idx & 511;
      short4v v;
      #pragma unroll
      for (int j = 0; j < 4; ++j) {
        const int c = ((cp + j) & 7) * 64 + ((cp + j) >> 3);
        v[j] = f32_to_bf_bits(w_proj[(size_t)o * C_ + c]);
      }
      *(short4v*)(wpp16 + (size_t)o * C_ + cp) = v;
    }
  }
}

// ---------------------------------------------------------------------------
// K2: xT[b][t][c] = bf16(x[b][c][t]*s[c] + t[c])  (BN folded into transpose)
// ---------------------------------------------------------------------------
__global__ __launch_bounds__(256) void xt_kernel(
    const float* __restrict__ x, const float* __restrict__ s,
    const float* __restrict__ t, short* __restrict__ xT)
{
  __shared__ float T[64][65];
  const int t0 = blockIdx.x * 64, c0 = blockIdx.y * 64, b = blockIdx.z;
  const int tid = threadIdx.x;
  const float* xp = x + (size_t)b * C_ * L_;
  #pragma unroll
  for (int it = 0; it < 16; ++it) {
    const int idx = it * 256 + tid;
    const int rr = idx >> 6, cc = idx & 63;  // rr = c-local, cc = t-local
    T[rr][cc] = fmaf(xp[(size_t)(c0 + rr) * L_ + t0 + cc], s[c0 + rr], t[c0 + rr]);
  }
  __syncthreads();
  #pragma unroll
  for (int it = 0; it < 16; ++it) {
    const int idx = it * 256 + tid;
    const int cc = idx >> 6, rr = idx & 63;
    xT[((size_t)b * L_ + t0 + cc) * C_ + c0 + rr] = f32_to_bf_bits(T[rr][cc]);
  }
}

// ---------------------------------------------------------------------------
// K3: bf16 MFMA GEMM, both operands row-major shared-K (B transposed form).
// C[m][n] = sum_k A[m][k] * B[n][k] + bias (+res for f32 out).
// 4 waves (2x2), BM=MR*32, BN=NR*32, BK=64; XOR slot-swizzle on LDS.
// ---------------------------------------------------------------------------
template <int MR, int NR, bool OUT_BF16>
__global__ __launch_bounds__(256) void gemm_bt16_kernel(
    const short* __restrict__ A, const short* __restrict__ B,
    const float* __restrict__ bias, const float* __restrict__ res,
    void* __restrict__ Cv, int M, int N, int K,
    size_t sB, size_t sC, size_t sR)
{
  constexpr int BM = MR * 32, BN = NR * 32;
  __shared__ short As[BM * 64];
  __shared__ short Bs[BN * 64];
  const int tid = threadIdx.x;
  const int l = tid & 63, w = tid >> 6;
  const int wr = w >> 1, wc = w & 1;
  const int ll = l & 15;
  const int n0 = blockIdx.x * BN, m0 = blockIdx.y * BM, bz = blockIdx.z;
  const short* Bg = B + (size_t)bz * sB;
  f32x4 acc[MR][NR] = {};

  for (int k0 = 0; k0 < K; k0 += 64) {
    #pragma unroll
    for (int it = 0; it < BM / 32; ++it) {
      const int i = it * 256 + tid;
      const int row = i >> 3, s = i & 7;
      const short8 va = *(const short8*)(A + (size_t)(m0 + row) * K + k0 + s * 8);
      *(short8*)(As + row * 64 + (s ^ (row & 7)) * 8) = va;
    }
    #pragma unroll
    for (int it = 0; it < BN / 32; ++it) {
      const int i = it * 256 + tid;
      const int row = i >> 3, s = i & 7;
      const short8 vb = *(const short8*)(Bg + (size_t)(n0 + row) * K + k0 + s * 8);
      *(short8*)(Bs + row * 64 + (s ^ (row & 7)) * 8) = vb;
    }
    __syncthreads();
    #pragma unroll
    for (int kk = 0; kk < 2; ++kk) {
      short8 af[MR], bfg[NR];
      const int sd = kk * 4 + (l >> 4);
      #pragma unroll
      for (int m = 0; m < MR; ++m) {
        const int ra = wr * MR * 16 + m * 16 + ll;
        af[m] = *(const short8*)(As + ra * 64 + (sd ^ (ra & 7)) * 8);
      }
      #pragma unroll
      for (int n = 0; n < NR; ++n) {
        const int rb = wc * NR * 16 + n * 16 + ll;
        bfg[n] = *(const short8*)(Bs + rb * 64 + (sd ^ (rb & 7)) * 8);
      }
      #pragma unroll
      for (int m = 0; m < MR; ++m)
        #pragma unroll
        for (int n = 0; n < NR; ++n)
          acc[m][n] = __builtin_amdgcn_mfma_f32_16x16x32_bf16(
              af[m], bfg[n], acc[m][n], 0, 0, 0);
    }
    __syncthreads();
  }

  // epilogue: D col = lane&15, row = 4*(lane>>4) + reg
  const int rg4 = (l >> 4) * 4;
  __hip_bfloat16* Cb = (__hip_bfloat16*)Cv + (size_t)bz * sC;
  float* Cf = (float*)Cv + (size_t)bz * sC;
  const float* Rp = res + (size_t)bz * sR;
  #pragma unroll
  for (int m = 0; m < MR; ++m) {
    #pragma unroll
    for (int reg = 0; reg < 4; ++reg) {
      const int gm = m0 + wr * MR * 16 + m * 16 + rg4 + reg;
      const float bv = bias[gm];
      #pragma unroll
      for (int n = 0; n < NR; ++n) {
        const int gn = n0 + wc * NR * 16 + n * 16 + ll;
        float v = acc[m][n][reg] + bv;
        if (OUT_BF16) {
          Cb[(size_t)gm * N + gn] = __hip_bfloat16_raw{(unsigned short)f32_to_bf_bits(v)};
        } else {
          v += Rp[(size_t)gm * N + gn];
          Cf[(size_t)gm * N + gn] = v;
        }
      }
    }
  }
}

// ---------------------------------------------------------------------------
// K4: MFMA attention. Round-8 structure with two VALU fixes:
//  (a) FEXP2 = raw v_exp_f32 (no denormal fixup sequence)
//  (b) ak loads unconditionally: bQ is zero for lanes>=16 (k=8..31), so the
//      B-side zeros annihilate whatever finite K data the A pad rows carry.
// ---------------------------------------------------------------------------
__global__ __launch_bounds__(256, 4) void attn_kernel(
    const __hip_bfloat16* __restrict__ qkv, short* __restrict__ hT)
{
  __shared__ short Klds[1024 * 8];    // [f][g] bf16, 16 KB (reused for O out)
  __shared__ __fp16 Vlds[8 * 1024];   // [g][f] f16, swizzled, 16 KB

  const int tq = blockIdx.x, d = blockIdx.y, b = blockIdx.z;
  const int tid = threadIdx.x;
  const int w = tid >> 6, l = tid & 63;
  const int lh = l >> 4, ll = l & 15;
  const int t0 = tq * 128 + w * 32;
  const short* base = (const short*)qkv + (size_t)b * OC_ * L_;
  short* VldsS = (short*)Vlds;

  // ---- stage K[f][g] (coalesced along f)
  #pragma unroll
  for (int it = 0; it < 4; ++it) {
    const int f = it * 256 + tid;
    short8 kv;
    #pragma unroll
    for (int g = 0; g < 8; ++g)
      kv[g] = base[(size_t)((8 + g) * HD_ + d) * L_ + f];
    *(short8*)(Klds + f * 8) = kv;
  }
  // ---- stage V[g][f] as f16, slot-swizzled within 16-slot windows
  #pragma unroll
  for (int it = 0; it < 4; ++it) {
    const int i = it * 256 + tid;
    const int g = i >> 7, fs = i & 127;
    const short8 v = *(const short8*)(
        base + (size_t)((16 + g) * HD_ + d) * L_ + fs * 8);
    unsigned u[4];
    #pragma unroll
    for (int e = 0; e < 4; ++e) {
      const f16x2 p = __builtin_amdgcn_cvt_pkrtz(
          bf_bits_to_f32((unsigned short)v[2 * e]),
          bf_bits_to_f32((unsigned short)v[2 * e + 1]));
      u[e] = __builtin_bit_cast(unsigned, p);
    }
    uint4 uu; uu.x = u[0]; uu.y = u[1]; uu.z = u[2]; uu.w = u[3];
    *(uint4*)(VldsS + g * 1024 + ((fs & ~15) + ((fs & 15) ^ g)) * 8) = uu;
  }

  // ---- Q B-fragments (lanes l<16): B[k=g][t], scale*log2e folded in
  short8 bQ[2] = {};
  if (l < 16) {
    #pragma unroll
    for (int tt = 0; tt < 2; ++tt) {
      const int t = t0 + tt * 16 + ll;
      short8 qv;
      #pragma unroll
      for (int g = 0; g < 8; ++g) {
        const float v = bf_bits_to_f32(
            (unsigned short)base[(size_t)(g * HD_ + d) * L_ + t]);
        qv[g] = f32_to_bf_bits(v * 0.29448889f);  // 24^-0.5 * log2(e)
      }
      bQ[tt] = qv;
    }
  }

  __syncthreads();  // K/V staged

  f16x4 vone, vzero;
  vone[0] = (__fp16)1.f; vone[1] = (__fp16)1.f;
  vone[2] = (__fp16)1.f; vone[3] = (__fp16)1.f;
  vzero[0] = (__fp16)0.f; vzero[1] = (__fp16)0.f;
  vzero[2] = (__fp16)0.f; vzero[3] = (__fp16)0.f;
  f32x4 accO[2] = {};

  for (int c = 0; c < 8; ++c) {
    // K fragments: unconditional load (pad rows annihilated by bQ zeros)
    short8 ak[8];
    #pragma unroll
    for (int ft = 0; ft < 8; ++ft)
      ak[ft] = *(const short8*)(Klds + (size_t)(c * 128 + ft * 16 + ll) * 8);
    // V fragments (A[g][f_local]; row 8 = ones -> denominator for free)
    f16x4 av[8];
    #pragma unroll
    for (int ft = 0; ft < 8; ++ft) {
      const int s16 = ft * 2 + (lh >> 1);
      const f16x4 raw = *(const f16x4*)(
          Vlds + (l & 7) * 1024 + c * 128 + ((s16 ^ (l & 7)) * 8) + (lh & 1) * 4);
      av[ft] = (ll < 8) ? raw : ((ll == 8) ? vone : vzero);
    }
    #pragma unroll
    for (int ft = 0; ft < 8; ++ft) {
      #pragma unroll
      for (int tt = 0; tt < 2; ++tt) {
        const f32x4 s = __builtin_amdgcn_mfma_f32_16x16x32_bf16(
            ak[ft], bQ[tt], (f32x4){0.f, 0.f, 0.f, 0.f}, 0, 0, 0);
        const f16x2 p0 = __builtin_amdgcn_cvt_pkrtz(FEXP2(s[0]), FEXP2(s[1]));
        const f16x2 p1 = __builtin_amdgcn_cvt_pkrtz(FEXP2(s[2]), FEXP2(s[3]));
        union { f16x4 v; uint2 u; } bp;
        bp.u.x = __builtin_bit_cast(unsigned, p0);
        bp.u.y = __builtin_bit_cast(unsigned, p1);
        accO[tt] = __builtin_amdgcn_mfma_f32_16x16x16f16(av[ft], bp.v, accO[tt], 0, 0, 0);
      }
    }
  }

  // ---- epilogue: D row 8 (lane 32+ll, reg 0) = denominator; O out via LDS
  __syncthreads();                 // all waves done with Klds
  short* Olds = Klds;              // [128][8]
  #pragma unroll
  for (int nt = 0; nt < 2; ++nt) {
    const float sum = __shfl(accO[nt][0], 32 + ll);
    const float inv = 1.f / sum;
    if (lh < 2) {
      const int tl = w * 32 + nt * 16 + ll;
      #pragma unroll
      for (int reg = 0; reg < 4; ++reg)
        Olds[tl * 8 + lh * 4 + reg] = f32_to_bf_bits(accO[nt][reg] * inv);
    }
  }
  __syncthreads();
  if (tid < 128) {
    const short8 ov = *(const short8*)(Olds + tid * 8);
    *(short8*)(hT + ((size_t)b * L_ + tq * 128 + tid) * C_ + d * 8) = ov;
  }
}

// ---------------------------------------------------------------------------
extern "C" void kernel_launch(void* const* d_in, const int* in_sizes, int n_in,
                              void* d_out, int out_size, void* d_ws, size_t ws_size,
                              hipStream_t stream) {
  (void)in_sizes; (void)n_in; (void)out_size; (void)ws_size;
  const float* x      = (const float*)d_in[0];
  const float* gamma  = (const float*)d_in[1];
  const float* beta   = (const float*)d_in[2];
  const float* w_qkv  = (const float*)d_in[3];
  const float* b_qkv  = (const float*)d_in[4];
  const float* w_proj = (const float*)d_in[5];
  const float* b_proj = (const float*)d_in[6];
  float* out = (float*)d_out;
  char* wsb = (char*)d_ws;

  // workspace layout (bytes), ~12 MB
  float* s_buf = (float*)(wsb + 0);                         // 2 KB
  float* t_buf = (float*)(wsb + 2048);                      // 2 KB
  short* wq16  = (short*)(wsb + 4096);                      // 1.5 MB
  short* wpp16 = (short*)(wsb + 4096 + 1572864);            // 0.5 MB
  short* xT    = (short*)(wsb + 4096 + 2097152);            // 2 MB
  short* qkv   = (short*)(wsb + 4096 + 4194304);            // 6 MB
  short* hT    = (short*)(wsb + 4096 + 10485760);           // 2 MB

  hipLaunchKernelGGL(prep_kernel, dim3(768), dim3(256), 0, stream,
                     x, gamma, beta, w_qkv, w_proj, s_buf, t_buf, wq16, wpp16);
  hipLaunchKernelGGL(xt_kernel, dim3(L_ / 64, C_ / 64, B_), dim3(256), 0, stream,
                     x, s_buf, t_buf, xT);
  // qkv[o][t] = wq16 @ xn + b_qkv   (64x64 tiles -> 768 blocks, 3/CU)
  hipLaunchKernelGGL((gemm_bt16_kernel<2, 2, true>),
                     dim3(L_ / 64, OC_ / 64, B_), dim3(256), 0, stream,
                     wq16, xT, b_qkv, (const float*)nullptr, (void*)qkv,
                     OC_, L_, C_, (size_t)L_ * C_, (size_t)OC_ * L_, (size_t)0);
  hipLaunchKernelGGL(attn_kernel, dim3(8, HD_, B_), dim3(256), 0, stream,
                     (const __hip_bfloat16*)qkv, hT);
  // out = wpp @ hT^T + b_proj + x
  hipLaunchKernelGGL((gemm_bt16_kernel<2, 2, false>),
                     dim3(L_ / 64, C_ / 64, B_), dim3(256), 0, stream,
                     wpp16, hT, b_proj, x, (void*)out,
                     C_, L_, C_, (size_t)L_ * C_, (size_t)C_ * L_, (size_t)C_ * L_);
}

// Round 10
// 49.181 us; speedup vs baseline: 2.1736x; 1.0882x over previous
//
#include <hip/hip_runtime.h>
#include <hip/hip_bf16.h>
#include <cstddef>
#include <cstdint>

#define B_ 2
#define C_ 512
#define L_ 1024
#define NH_ 8
#define HD_ 64
#define OC_ 1536  // 3*C

typedef short short8 __attribute__((ext_vector_type(8)));
typedef short short4v __attribute__((ext_vector_type(4)));
typedef float f32x4 __attribute__((ext_vector_type(4)));
typedef __fp16 f16x4 __attribute__((ext_vector_type(4)));
typedef __fp16 f16x2 __attribute__((ext_vector_type(2)));

// Fast 2^x: raw v_exp_f32 (no IEEE denormal fixup sequence).
#if defined(__has_builtin)
#if __has_builtin(__builtin_amdgcn_exp2f)
#define FEXP2(x) __builtin_amdgcn_exp2f(x)
#endif
#endif
#ifndef FEXP2
#define FEXP2(x) exp2f(x)
#endif

__device__ inline float bf_bits_to_f32(unsigned short u) {
  union { unsigned u32; float f; } c; c.u32 = ((unsigned)u) << 16; return c.f;
}
__device__ inline short f32_to_bf_bits(float f) {
  union { float f; unsigned u; } c; c.f = f;
  return (short)((c.u + 0x7FFFu + ((c.u >> 16) & 1u)) >> 16);
}

// async global->LDS, 16B per lane; LDS dest = wave-uniform base + lane*16.
__device__ __forceinline__ void gl2lds16(const short* g, short* l) {
  __builtin_amdgcn_global_load_lds(
      (const __attribute__((address_space(1))) unsigned*)(const void*)g,
      (__attribute__((address_space(3))) unsigned*)(void*)l, 16, 0, 0);
}

// ---------------------------------------------------------------------------
// K1 prep: blocks 0-511: BN stats -> s,t. 512-703: w_qkv -> bf16.
//          704-767: w_proj permuted cols -> bf16 (wpp[o][d*8+g]).
// ---------------------------------------------------------------------------
__global__ __launch_bounds__(256) void prep_kernel(
    const float* __restrict__ x, const float* __restrict__ gamma,
    const float* __restrict__ beta, const float* __restrict__ w_qkv,
    const float* __restrict__ w_proj,
    float* __restrict__ s_out, float* __restrict__ t_out,
    short* __restrict__ wq16, short* __restrict__ wpp16)
{
  const int bid = blockIdx.x;
  const int tid = threadIdx.x;
  if (bid < 512) {
    const int ch = bid;
    const float4 v0 = *(const float4*)(x + (size_t)ch * L_ + tid * 4);
    const float4 v1 = *(const float4*)(x + (size_t)(C_ + ch) * L_ + tid * 4);
    float s1 = v0.x + v0.y + v0.z + v0.w + v1.x + v1.y + v1.z + v1.w;
    float s2 = v0.x*v0.x + v0.y*v0.y + v0.z*v0.z + v0.w*v0.w
             + v1.x*v1.x + v1.y*v1.y + v1.z*v1.z + v1.w*v1.w;
    #pragma unroll
    for (int off = 32; off > 0; off >>= 1) {
      s1 += __shfl_down(s1, off);
      s2 += __shfl_down(s2, off);
    }
    __shared__ float r1[4], r2[4];
    const int wid = tid >> 6, lane = tid & 63;
    if (lane == 0) { r1[wid] = s1; r2[wid] = s2; }
    __syncthreads();
    if (tid == 0) {
      const float S1 = r1[0] + r1[1] + r1[2] + r1[3];
      const float S2 = r2[0] + r2[1] + r2[2] + r2[3];
      const float invN = 1.f / (float)(B_ * L_);
      const float mean = S1 * invN;
      const float var  = S2 * invN - mean * mean;  // biased
      const float rstd = rsqrtf(var + 1e-5f);
      const float sc = gamma[ch] * rstd;
      s_out[ch] = sc;
      t_out[ch] = beta[ch] - mean * sc;
    }
  } else if (bid < 704) {
    const int base = (bid - 512) * 4096 + tid * 16;
    #pragma unroll
    for (int it = 0; it < 2; ++it) {
      const float4 a0 = *(const float4*)(w_qkv + base + it * 8);
      const float4 a1 = *(const float4*)(w_qkv + base + it * 8 + 4);
      short8 v;
      v[0] = f32_to_bf_bits(a0.x); v[1] = f32_to_bf_bits(a0.y);
      v[2] = f32_to_bf_bits(a0.z); v[3] = f32_to_bf_bits(a0.w);
      v[4] = f32_to_bf_bits(a1.x); v[5] = f32_to_bf_bits(a1.y);
      v[6] = f32_to_bf_bits(a1.z); v[7] = f32_to_bf_bits(a1.w);
      *(short8*)(wq16 + base + it * 8) = v;
    }
  } else {
    // wpp[o][c'] = w[o][(c'&7)*64+(c'>>3)]
    #pragma unroll
    for (int grp = 0; grp < 4; ++grp) {
      const int idx = (bid - 704) * 4096 + tid * 16 + grp * 4;
      const int o = idx >> 9, cp = idx & 511;
      short4v v;
      #pragma unroll
      for (int j = 0; j < 4; ++j) {
        const int c = ((cp + j) & 7) * 64 + ((cp + j) >> 3);
        v[j] = f32_to_bf_bits(w_proj[(size_t)o * C_ + c]);
      }
      *(short4v*)(wpp16 + (size_t)o * C_ + cp) = v;
    }
  }
}

// ---------------------------------------------------------------------------
// K2: xT[b][t][c] = bf16(x[b][c][t]*s[c] + t[c])  (BN folded into transpose)
// ---------------------------------------------------------------------------
__global__ __launch_bounds__(256) void xt_kernel(
    const float* __restrict__ x, const float* __restrict__ s,
    const float* __restrict__ t, short* __restrict__ xT)
{
  __shared__ float T[64][65];
  const int t0 = blockIdx.x * 64, c0 = blockIdx.y * 64, b = blockIdx.z;
  const int tid = threadIdx.x;
  const float* xp = x + (size_t)b * C_ * L_;
  #pragma unroll
  for (int it = 0; it < 4; ++it) {
    const int idx = it * 256 + tid;
    const int rr = idx >> 4, c4 = (idx & 15) * 4;  // rr = c-local, c4 = t-local
    const float4 v = *(const float4*)(xp + (size_t)(c0 + rr) * L_ + t0 + c4);
    const float sc = s[c0 + rr], tc = t[c0 + rr];
    T[rr][c4 + 0] = fmaf(v.x, sc, tc);
    T[rr][c4 + 1] = fmaf(v.y, sc, tc);
    T[rr][c4 + 2] = fmaf(v.z, sc, tc);
    T[rr][c4 + 3] = fmaf(v.w, sc, tc);
  }
  __syncthreads();
  #pragma unroll
  for (int it = 0; it < 4; ++it) {
    const int idx = it * 256 + tid;
    const int tt_ = idx >> 4, cc4 = (idx & 15) * 4;
    short4v o;
    #pragma unroll
    for (int j = 0; j < 4; ++j) o[j] = f32_to_bf_bits(T[cc4 + j][tt_]);
    *(short4v*)(xT + ((size_t)b * L_ + t0 + tt_) * C_ + c0 + cc4) = o;
  }
}

// ---------------------------------------------------------------------------
// K3: bf16 MFMA GEMM, both operands row-major shared-K.
// C[m][n] = sum_k A[m][k]*B[n][k] + bias (+res for f32 out).
// Staging via global_load_lds width-16: LINEAR LDS dest, per-lane source
// pre-applies the XOR slot swizzle (inverse == forward; involution), so the
// compute-side reads (slot sd ^ (row&7)) see global[row][sd].  [rule #21]
// ---------------------------------------------------------------------------
template <int MR, int NR, bool OUT_BF16>
__global__ __launch_bounds__(256) void gemm_bt16_kernel(
    const short* __restrict__ A, const short* __restrict__ B,
    const float* __restrict__ bias, const float* __restrict__ res,
    void* __restrict__ Cv, int M, int N, int K,
    size_t sB, size_t sC, size_t sR)
{
  constexpr int BM = MR * 32, BN = NR * 32;
  __shared__ short As[BM * 64];
  __shared__ short Bs[BN * 64];
  const int tid = threadIdx.x;
  const int l = tid & 63, w = tid >> 6;
  const int wr = w >> 1, wc = w & 1;
  const int ll = l & 15;
  const int n0 = blockIdx.x * BN, m0 = blockIdx.y * BM, bz = blockIdx.z;
  const short* Bg = B + (size_t)bz * sB;
  f32x4 acc[MR][NR] = {};

  for (int k0 = 0; k0 < K; k0 += 64) {
    // ---- async stage: each inst = 8 rows x 128B; wave w owns a row stripe
    #pragma unroll
    for (int it = 0; it < BM / 32; ++it) {
      const int row0 = w * (BM / 4) + it * 8;
      const int row = row0 + (l >> 3), sl = l & 7;
      gl2lds16(A + (size_t)(m0 + row) * K + k0 + ((sl ^ (row & 7)) * 8),
               As + row0 * 64);
    }
    #pragma unroll
    for (int it = 0; it < BN / 32; ++it) {
      const int row0 = w * (BN / 4) + it * 8;
      const int row = row0 + (l >> 3), sl = l & 7;
      gl2lds16(Bg + (size_t)(n0 + row) * K + k0 + ((sl ^ (row & 7)) * 8),
               Bs + row0 * 64);
    }
    __syncthreads();  // drains vmcnt (compiler emits s_waitcnt before barrier)
    #pragma unroll
    for (int kk = 0; kk < 2; ++kk) {
      short8 af[MR], bfg[NR];
      const int sd = kk * 4 + (l >> 4);
      #pragma unroll
      for (int m = 0; m < MR; ++m) {
        const int ra = wr * MR * 16 + m * 16 + ll;
        af[m] = *(const short8*)(As + ra * 64 + (sd ^ (ra & 7)) * 8);
      }
      #pragma unroll
      for (int n = 0; n < NR; ++n) {
        const int rb = wc * NR * 16 + n * 16 + ll;
        bfg[n] = *(const short8*)(Bs + rb * 64 + (sd ^ (rb & 7)) * 8);
      }
      #pragma unroll
      for (int m = 0; m < MR; ++m)
        #pragma unroll
        for (int n = 0; n < NR; ++n)
          acc[m][n] = __builtin_amdgcn_mfma_f32_16x16x32_bf16(
              af[m], bfg[n], acc[m][n], 0, 0, 0);
    }
    __syncthreads();
  }

  // epilogue: D col = lane&15, row = 4*(lane>>4) + reg
  const int rg4 = (l >> 4) * 4;
  __hip_bfloat16* Cb = (__hip_bfloat16*)Cv + (size_t)bz * sC;
  float* Cf = (float*)Cv + (size_t)bz * sC;
  const float* Rp = res + (size_t)bz * sR;
  #pragma unroll
  for (int m = 0; m < MR; ++m) {
    #pragma unroll
    for (int reg = 0; reg < 4; ++reg) {
      const int gm = m0 + wr * MR * 16 + m * 16 + rg4 + reg;
      const float bv = bias[gm];
      #pragma unroll
      for (int n = 0; n < NR; ++n) {
        const int gn = n0 + wc * NR * 16 + n * 16 + ll;
        float v = acc[m][n][reg] + bv;
        if (OUT_BF16) {
          Cb[(size_t)gm * N + gn] = __hip_bfloat16_raw{(unsigned short)f32_to_bf_bits(v)};
        } else {
          v += Rp[(size_t)gm * N + gn];
          Cf[(size_t)gm * N + gn] = v;
        }
      }
    }
  }
}

// ---------------------------------------------------------------------------
// K4: MFMA attention. Vlds now [9][1024] f16 (rows 0-7 = V, row 8 = ones for
// the free denominator); PV A-rows 9-15 only affect D rows we never read, so
// lanes ll>8 clamp to row 8 (hoisted, lane-constant) -- no per-ft selects.
// LDS 34 KB -> 4 blocks/CU.
// ---------------------------------------------------------------------------
__global__ __launch_bounds__(256, 4) void attn_kernel(
    const __hip_bfloat16* __restrict__ qkv, short* __restrict__ hT)
{
  __shared__ short Klds[1024 * 8];    // [f][g] bf16, 16 KB (reused for O out)
  __shared__ __fp16 Vlds[9 * 1024];   // [g][f] f16, swizzled, 18 KB

  const int tq = blockIdx.x, d = blockIdx.y, b = blockIdx.z;
  const int tid = threadIdx.x;
  const int w = tid >> 6, l = tid & 63;
  const int lh = l >> 4, ll = l & 15;
  const int t0 = tq * 128 + w * 32;
  const short* base = (const short*)qkv + (size_t)b * OC_ * L_;
  short* VldsS = (short*)Vlds;

  // ---- stage K[f][g] (coalesced along f)
  #pragma unroll
  for (int it = 0; it < 4; ++it) {
    const int f = it * 256 + tid;
    short8 kv;
    #pragma unroll
    for (int g = 0; g < 8; ++g)
      kv[g] = base[(size_t)((8 + g) * HD_ + d) * L_ + f];
    *(short8*)(Klds + f * 8) = kv;
  }
  // ---- stage V[g][f] as f16, slot-swizzled within 16-slot windows
  #pragma unroll
  for (int it = 0; it < 4; ++it) {
    const int i = it * 256 + tid;
    const int g = i >> 7, fs = i & 127;
    const short8 v = *(const short8*)(
        base + (size_t)((16 + g) * HD_ + d) * L_ + fs * 8);
    unsigned u[4];
    #pragma unroll
    for (int e = 0; e < 4; ++e) {
      const f16x2 p = __builtin_amdgcn_cvt_pkrtz(
          bf_bits_to_f32((unsigned short)v[2 * e]),
          bf_bits_to_f32((unsigned short)v[2 * e + 1]));
      u[e] = __builtin_bit_cast(unsigned, p);
    }
    uint4 uu; uu.x = u[0]; uu.y = u[1]; uu.z = u[2]; uu.w = u[3];
    *(uint4*)(VldsS + g * 1024 + ((fs & ~15) + ((fs & 15) ^ g)) * 8) = uu;
  }
  // ---- row 8 = ones (f16 1.0 = 0x3C00): denominator via MFMA
  {
    uint2 ones; ones.x = 0x3C003C00u; ones.y = 0x3C003C00u;
    *(uint2*)(VldsS + 8 * 1024 + tid * 4) = ones;
  }

  // ---- Q B-fragments (lanes l<16): B[k=g][t], scale*log2e folded in
  short8 bQ[2] = {};
  if (l < 16) {
    #pragma unroll
    for (int tt = 0; tt < 2; ++tt) {
      const int t = t0 + tt * 16 + ll;
      short8 qv;
      #pragma unroll
      for (int g = 0; g < 8; ++g) {
        const float v = bf_bits_to_f32(
            (unsigned short)base[(size_t)(g * HD_ + d) * L_ + t]);
        qv[g] = f32_to_bf_bits(v * 0.29448889f);  // 24^-0.5 * log2(e)
      }
      bQ[tt] = qv;
    }
  }

  __syncthreads();  // K/V staged

  const int vrow = (ll < 9) ? ll : 8;  // lane-constant PV A-row
  f32x4 accO[2] = {};

  for (int c = 0; c < 8; ++c) {
    short8 ak[8];
    #pragma unroll
    for (int ft = 0; ft < 8; ++ft)
      ak[ft] = *(const short8*)(Klds + (size_t)(c * 128 + ft * 16 + ll) * 8);
    f16x4 av[8];
    #pragma unroll
    for (int ft = 0; ft < 8; ++ft) {
      const int s16 = ft * 2 + (lh >> 1);
      av[ft] = *(const f16x4*)(
          Vlds + vrow * 1024 + c * 128 + ((s16 ^ (vrow & 7)) * 8) + (lh & 1) * 4);
    }
    #pragma unroll
    for (int ft = 0; ft < 8; ++ft) {
      #pragma unroll
      for (int tt = 0; tt < 2; ++tt) {
        const f32x4 s = __builtin_amdgcn_mfma_f32_16x16x32_bf16(
            ak[ft], bQ[tt], (f32x4){0.f, 0.f, 0.f, 0.f}, 0, 0, 0);
        const f16x2 p0 = __builtin_amdgcn_cvt_pkrtz(FEXP2(s[0]), FEXP2(s[1]));
        const f16x2 p1 = __builtin_amdgcn_cvt_pkrtz(FEXP2(s[2]), FEXP2(s[3]));
        union { f16x4 v; uint2 u; } bp;
        bp.u.x = __builtin_bit_cast(unsigned, p0);
        bp.u.y = __builtin_bit_cast(unsigned, p1);
        accO[tt] = __builtin_amdgcn_mfma_f32_16x16x16f16(av[ft], bp.v, accO[tt], 0, 0, 0);
      }
    }
  }

  // ---- epilogue: D row 8 (lane 32+ll, reg 0) = denominator; O out via LDS
  __syncthreads();                 // all waves done with Klds
  short* Olds = Klds;              // [128][8]
  #pragma unroll
  for (int nt = 0; nt < 2; ++nt) {
    const float sum = __shfl(accO[nt][0], 32 + ll);
    const float inv = 1.f / sum;
    if (lh < 2) {
      const int tl = w * 32 + nt * 16 + ll;
      #pragma unroll
      for (int reg = 0; reg < 4; ++reg)
        Olds[tl * 8 + lh * 4 + reg] = f32_to_bf_bits(accO[nt][reg] * inv);
    }
  }
  __syncthreads();
  if (tid < 128) {
    const short8 ov = *(const short8*)(Olds + tid * 8);
    *(short8*)(hT + ((size_t)b * L_ + tq * 128 + tid) * C_ + d * 8) = ov;
  }
}

// ---------------------------------------------------------------------------
extern "C" void kernel_launch(void* const* d_in, const int* in_sizes, int n_in,
                              void* d_out, int out_size, void* d_ws, size_t ws_size,
                              hipStream_t stream) {
  (void)in_sizes; (void)n_in; (void)out_size; (void)ws_size;
  const float* x      = (const float*)d_in[0];
  const float* gamma  = (const float*)d_in[1];
  const float* beta   = (const float*)d_in[2];
  const float* w_qkv  = (const float*)d_in[3];
  const float* b_qkv  = (const float*)d_in[4];
  const float* w_proj = (const float*)d_in[5];
  const float* b_proj = (const float*)d_in[6];
  float* out = (float*)d_out;
  char* wsb = (char*)d_ws;

  // workspace layout (bytes), ~12 MB
  float* s_buf = (float*)(wsb + 0);                         // 2 KB
  float* t_buf = (float*)(wsb + 2048);                      // 2 KB
  short* wq16  = (short*)(wsb + 4096);                      // 1.5 MB
  short* wpp16 = (short*)(wsb + 4096 + 1572864);            // 0.5 MB
  short* xT    = (short*)(wsb + 4096 + 2097152);            // 2 MB
  short* qkv   = (short*)(wsb + 4096 + 4194304);            // 6 MB
  short* hT    = (short*)(wsb + 4096 + 10485760);           // 2 MB

  hipLaunchKernelGGL(prep_kernel, dim3(768), dim3(256), 0, stream,
                     x, gamma, beta, w_qkv, w_proj, s_buf, t_buf, wq16, wpp16);
  hipLaunchKernelGGL(xt_kernel, dim3(L_ / 64, C_ / 64, B_), dim3(256), 0, stream,
                     x, s_buf, t_buf, xT);
  // qkv[o][t] = wq16 @ xn + b_qkv   (64x64 tiles, 768 blocks = 3/CU)
  hipLaunchKernelGGL((gemm_bt16_kernel<2, 2, true>),
                     dim3(L_ / 64, OC_ / 64, B_), dim3(256), 0, stream,
                     wq16, xT, b_qkv, (const float*)nullptr, (void*)qkv,
                     OC_, L_, C_, (size_t)L_ * C_, (size_t)OC_ * L_, (size_t)0);
  hipLaunchKernelGGL(attn_kernel, dim3(8, HD_, B_), dim3(256), 0, stream,
                     (const __hip_bfloat16*)qkv, hT);
  // out = wpp @ hT^T + b_proj + x   (32x64 tiles, 512 blocks = 2/CU)
  hipLaunchKernelGGL((gemm_bt16_kernel<1, 2, false>),
                     dim3(L_ / 64, C_ / 32, B_), dim3(256), 0, stream,
                     wpp16, hT, b_proj, x, (void*)out,
                     C_, L_, C_, (size_t)L_ * C_, (size_t)C_ * L_, (size_t)C_ * L_);
}

// Round 12
// 48.944 us; speedup vs baseline: 2.1842x; 1.0048x over previous
//
#include <hip/hip_runtime.h>
#include <hip/hip_bf16.h>
#include <cstddef>
#include <cstdint>

#define B_ 2
#define C_ 512
#define L_ 1024
#define NH_ 8
#define HD_ 64
#define OC_ 1536  // 3*C

typedef short short8 __attribute__((ext_vector_type(8)));
typedef short short4v __attribute__((ext_vector_type(4)));
typedef float f32x4 __attribute__((ext_vector_type(4)));
typedef __fp16 f16x4 __attribute__((ext_vector_type(4)));
typedef __fp16 f16x2 __attribute__((ext_vector_type(2)));

// Fast 2^x: raw v_exp_f32 (no IEEE denormal fixup sequence).
#if defined(__has_builtin)
#if __has_builtin(__builtin_amdgcn_exp2f)
#define FEXP2(x) __builtin_amdgcn_exp2f(x)
#endif
#endif
#ifndef FEXP2
#define FEXP2(x) exp2f(x)
#endif

__device__ inline float bf_bits_to_f32(unsigned short u) {
  union { unsigned u32; float f; } c; c.u32 = ((unsigned)u) << 16; return c.f;
}
__device__ inline short f32_to_bf_bits(float f) {
  union { float f; unsigned u; } c; c.f = f;
  return (short)((c.u + 0x7FFFu + ((c.u >> 16) & 1u)) >> 16);
}

// async global->LDS, 16B per lane; LDS dest = wave-uniform base + lane*16.
__device__ __forceinline__ void gl2lds16(const short* g, short* l) {
  __builtin_amdgcn_global_load_lds(
      (const __attribute__((address_space(1))) unsigned*)(const void*)g,
      (__attribute__((address_space(3))) unsigned*)(void*)l, 16, 0, 0);
}

// ---------------------------------------------------------------------------
// K1 prep: blocks 0-511: BN stats -> s,t. 512-703: w_qkv -> bf16.
//          704-767: w_proj permuted cols -> bf16 (wpp[o][d*8+g]).
// ---------------------------------------------------------------------------
__global__ __launch_bounds__(256) void prep_kernel(
    const float* __restrict__ x, const float* __restrict__ gamma,
    const float* __restrict__ beta, const float* __restrict__ w_qkv,
    const float* __restrict__ w_proj,
    float* __restrict__ s_out, float* __restrict__ t_out,
    short* __restrict__ wq16, short* __restrict__ wpp16)
{
  const int bid = blockIdx.x;
  const int tid = threadIdx.x;
  if (bid < 512) {
    const int ch = bid;
    const float4 v0 = *(const float4*)(x + (size_t)ch * L_ + tid * 4);
    const float4 v1 = *(const float4*)(x + (size_t)(C_ + ch) * L_ + tid * 4);
    float s1 = v0.x + v0.y + v0.z + v0.w + v1.x + v1.y + v1.z + v1.w;
    float s2 = v0.x*v0.x + v0.y*v0.y + v0.z*v0.z + v0.w*v0.w
             + v1.x*v1.x + v1.y*v1.y + v1.z*v1.z + v1.w*v1.w;
    #pragma unroll
    for (int off = 32; off > 0; off >>= 1) {
      s1 += __shfl_down(s1, off);
      s2 += __shfl_down(s2, off);
    }
    __shared__ float r1[4], r2[4];
    const int wid = tid >> 6, lane = tid & 63;
    if (lane == 0) { r1[wid] = s1; r2[wid] = s2; }
    __syncthreads();
    if (tid == 0) {
      const float S1 = r1[0] + r1[1] + r1[2] + r1[3];
      const float S2 = r2[0] + r2[1] + r2[2] + r2[3];
      const float invN = 1.f / (float)(B_ * L_);
      const float mean = S1 * invN;
      const float var  = S2 * invN - mean * mean;  // biased
      const float rstd = rsqrtf(var + 1e-5f);
      const float sc = gamma[ch] * rstd;
      s_out[ch] = sc;
      t_out[ch] = beta[ch] - mean * sc;
    }
  } else if (bid < 704) {
    const int base = (bid - 512) * 4096 + tid * 16;
    #pragma unroll
    for (int it = 0; it < 2; ++it) {
      const float4 a0 = *(const float4*)(w_qkv + base + it * 8);
      const float4 a1 = *(const float4*)(w_qkv + base + it * 8 + 4);
      short8 v;
      v[0] = f32_to_bf_bits(a0.x); v[1] = f32_to_bf_bits(a0.y);
      v[2] = f32_to_bf_bits(a0.z); v[3] = f32_to_bf_bits(a0.w);
      v[4] = f32_to_bf_bits(a1.x); v[5] = f32_to_bf_bits(a1.y);
      v[6] = f32_to_bf_bits(a1.z); v[7] = f32_to_bf_bits(a1.w);
      *(short8*)(wq16 + base + it * 8) = v;
    }
  } else {
    // wpp[o][c'] = w[o][(c'&7)*64+(c'>>3)]
    #pragma unroll
    for (int grp = 0; grp < 4; ++grp) {
      const int idx = (bid - 704) * 4096 + tid * 16 + grp * 4;
      const int o = idx >> 9, cp = idx & 511;
      short4v v;
      #pragma unroll
      for (int j = 0; j < 4; ++j) {
        const int c = ((cp + j) & 7) * 64 + ((cp + j) >> 3);
        v[j] = f32_to_bf_bits(w_proj[(size_t)o * C_ + c]);
      }
      *(short4v*)(wpp16 + (size_t)o * C_ + cp) = v;
    }
  }
}

// ---------------------------------------------------------------------------
// K2: xT[b][t][c] = bf16(x[b][c][t]*s[c] + t[c])  (BN folded into transpose)
// ---------------------------------------------------------------------------
__global__ __launch_bounds__(256) void xt_kernel(
    const float* __restrict__ x, const float* __restrict__ s,
    const float* __restrict__ t, short* __restrict__ xT)
{
  __shared__ float T[64][65];
  const int t0 = blockIdx.x * 64, c0 = blockIdx.y * 64, b = blockIdx.z;
  const int tid = threadIdx.x;
  const float* xp = x + (size_t)b * C_ * L_;
  #pragma unroll
  for (int it = 0; it < 4; ++it) {
    const int idx = it * 256 + tid;
    const int rr = idx >> 4, c4 = (idx & 15) * 4;  // rr = c-local, c4 = t-local
    const float4 v = *(const float4*)(xp + (size_t)(c0 + rr) * L_ + t0 + c4);
    const float sc = s[c0 + rr], tc = t[c0 + rr];
    T[rr][c4 + 0] = fmaf(v.x, sc, tc);
    T[rr][c4 + 1] = fmaf(v.y, sc, tc);
    T[rr][c4 + 2] = fmaf(v.z, sc, tc);
    T[rr][c4 + 3] = fmaf(v.w, sc, tc);
  }
  __syncthreads();
  #pragma unroll
  for (int it = 0; it < 4; ++it) {
    const int idx = it * 256 + tid;
    const int tt_ = idx >> 4, cc4 = (idx & 15) * 4;
    short4v o;
    #pragma unroll
    for (int j = 0; j < 4; ++j) o[j] = f32_to_bf_bits(T[cc4 + j][tt_]);
    *(short4v*)(xT + ((size_t)b * L_ + t0 + tt_) * C_ + c0 + cc4) = o;
  }
}

// ---------------------------------------------------------------------------
// K3: bf16 MFMA GEMM, both operands row-major shared-K (unchanged from r10).
// ---------------------------------------------------------------------------
template <int MR, int NR, bool OUT_BF16>
__global__ __launch_bounds__(256) void gemm_bt16_kernel(
    const short* __restrict__ A, const short* __restrict__ B,
    const float* __restrict__ bias, const float* __restrict__ res,
    void* __restrict__ Cv, int M, int N, int K,
    size_t sB, size_t sC, size_t sR)
{
  constexpr int BM = MR * 32, BN = NR * 32;
  __shared__ short As[BM * 64];
  __shared__ short Bs[BN * 64];
  const int tid = threadIdx.x;
  const int l = tid & 63, w = tid >> 6;
  const int wr = w >> 1, wc = w & 1;
  const int ll = l & 15;
  const int n0 = blockIdx.x * BN, m0 = blockIdx.y * BM, bz = blockIdx.z;
  const short* Bg = B + (size_t)bz * sB;
  f32x4 acc[MR][NR] = {};

  for (int k0 = 0; k0 < K; k0 += 64) {
    #pragma unroll
    for (int it = 0; it < BM / 32; ++it) {
      const int row0 = w * (BM / 4) + it * 8;
      const int row = row0 + (l >> 3), sl = l & 7;
      gl2lds16(A + (size_t)(m0 + row) * K + k0 + ((sl ^ (row & 7)) * 8),
               As + row0 * 64);
    }
    #pragma unroll
    for (int it = 0; it < BN / 32; ++it) {
      const int row0 = w * (BN / 4) + it * 8;
      const int row = row0 + (l >> 3), sl = l & 7;
      gl2lds16(Bg + (size_t)(n0 + row) * K + k0 + ((sl ^ (row & 7)) * 8),
               Bs + row0 * 64);
    }
    __syncthreads();
    #pragma unroll
    for (int kk = 0; kk < 2; ++kk) {
      short8 af[MR], bfg[NR];
      const int sd = kk * 4 + (l >> 4);
      #pragma unroll
      for (int m = 0; m < MR; ++m) {
        const int ra = wr * MR * 16 + m * 16 + ll;
        af[m] = *(const short8*)(As + ra * 64 + (sd ^ (ra & 7)) * 8);
      }
      #pragma unroll
      for (int n = 0; n < NR; ++n) {
        const int rb = wc * NR * 16 + n * 16 + ll;
        bfg[n] = *(const short8*)(Bs + rb * 64 + (sd ^ (rb & 7)) * 8);
      }
      #pragma unroll
      for (int m = 0; m < MR; ++m)
        #pragma unroll
        for (int n = 0; n < NR; ++n)
          acc[m][n] = __builtin_amdgcn_mfma_f32_16x16x32_bf16(
              af[m], bfg[n], acc[m][n], 0, 0, 0);
    }
    __syncthreads();
  }

  const int rg4 = (l >> 4) * 4;
  __hip_bfloat16* Cb = (__hip_bfloat16*)Cv + (size_t)bz * sC;
  float* Cf = (float*)Cv + (size_t)bz * sC;
  const float* Rp = res + (size_t)bz * sR;
  #pragma unroll
  for (int m = 0; m < MR; ++m) {
    #pragma unroll
    for (int reg = 0; reg < 4; ++reg) {
      const int gm = m0 + wr * MR * 16 + m * 16 + rg4 + reg;
      const float bv = bias[gm];
      #pragma unroll
      for (int n = 0; n < NR; ++n) {
        const int gn = n0 + wc * NR * 16 + n * 16 + ll;
        float v = acc[m][n][reg] + bv;
        if (OUT_BF16) {
          Cb[(size_t)gm * N + gn] = __hip_bfloat16_raw{(unsigned short)f32_to_bf_bits(v)};
        } else {
          v += Rp[(size_t)gm * N + gn];
          Cf[(size_t)gm * N + gn] = v;
        }
      }
    }
  }
}

// ---------------------------------------------------------------------------
// K4: MFMA attention v4.1 — instruction diet (r11) + OOB fix.
//  * QK uses mfma_f32_16x16x16f16 (K=16; true K=8). Lanes hi>=2 supply
//    k=8..15, whose B-side (bQ) is zero; their A reads are CLAMPED to the
//    hi&1 slot so every DS read is in-bounds and finite (r11 bug: 4*hi
//    overran Klds by up to 8 elements -> garbage bits -> f16 NaN -> NaN*0
//    = NaN poisoned D rows 9-15 -> exp2 -> PV).
//  * Vlds padded [9][1032] (row stride 516 words: rows on distinct banks).
//  * c-loop fully unrolled: literal ds_read offsets off hoisted bases.
//  * Row 8 of Vlds = ones -> PV D-row 8 = softmax denominator for free.
// ---------------------------------------------------------------------------
__global__ __launch_bounds__(256, 4) void attn_kernel(
    const __hip_bfloat16* __restrict__ qkv, short* __restrict__ hT)
{
  __shared__ __fp16 Klds[1024 * 8];   // [f][g] f16, 16 KB (reused for O out)
  __shared__ __fp16 Vlds[9 * 1032];   // [g][f] f16, padded rows, ~18.1 KB

  const int tq = blockIdx.x, d = blockIdx.y, b = blockIdx.z;
  const int tid = threadIdx.x;
  const int w = tid >> 6, l = tid & 63;
  const int hi = l >> 4, ll = l & 15;
  const int t0 = tq * 128 + w * 32;
  const short* base = (const short*)qkv + (size_t)b * OC_ * L_;
  short* KldsS = (short*)Klds;
  short* VldsS = (short*)Vlds;

  // ---- stage K[f][g] as f16 (coalesced along f)
  #pragma unroll
  for (int it = 0; it < 4; ++it) {
    const int f = it * 256 + tid;
    unsigned u[4];
    #pragma unroll
    for (int e = 0; e < 4; ++e) {
      const f16x2 p = __builtin_amdgcn_cvt_pkrtz(
          bf_bits_to_f32((unsigned short)base[(size_t)((8 + 2*e)   * HD_ + d) * L_ + f]),
          bf_bits_to_f32((unsigned short)base[(size_t)((8 + 2*e+1) * HD_ + d) * L_ + f]));
      u[e] = __builtin_bit_cast(unsigned, p);
    }
    uint4 uu; uu.x = u[0]; uu.y = u[1]; uu.z = u[2]; uu.w = u[3];
    *(uint4*)(KldsS + f * 8) = uu;
  }
  // ---- stage V[g][f] as f16, padded rows (no swizzle)
  #pragma unroll
  for (int it = 0; it < 4; ++it) {
    const int i = it * 256 + tid;
    const int g = i >> 7, fs = i & 127;
    const short8 v = *(const short8*)(
        base + (size_t)((16 + g) * HD_ + d) * L_ + fs * 8);
    unsigned u[4];
    #pragma unroll
    for (int e = 0; e < 4; ++e) {
      const f16x2 p = __builtin_amdgcn_cvt_pkrtz(
          bf_bits_to_f32((unsigned short)v[2 * e]),
          bf_bits_to_f32((unsigned short)v[2 * e + 1]));
      u[e] = __builtin_bit_cast(unsigned, p);
    }
    uint4 uu; uu.x = u[0]; uu.y = u[1]; uu.z = u[2]; uu.w = u[3];
    *(uint4*)(VldsS + g * 1032 + fs * 8) = uu;
  }
  // ---- row 8 = ones (f16 1.0 = 0x3C00): denominator via MFMA
  {
    uint2 ones; ones.x = 0x3C003C00u; ones.y = 0x3C003C00u;
    *(uint2*)(VldsS + 8 * 1032 + tid * 4) = ones;
  }

  // ---- Q B-fragments (lanes l<32): B[k=4*hi+j][t], scale*log2e folded in
  f16x4 bQ[2] = {};
  if (l < 32) {
    const int g0 = 4 * hi;  // hi in {0,1}
    #pragma unroll
    for (int tt = 0; tt < 2; ++tt) {
      const int t = t0 + tt * 16 + ll;
      float q[4];
      #pragma unroll
      for (int j = 0; j < 4; ++j)
        q[j] = bf_bits_to_f32(
                   (unsigned short)base[(size_t)((g0 + j) * HD_ + d) * L_ + t]) *
               0.29448889f;  // 24^-0.5 * log2(e)
      const f16x2 a = __builtin_amdgcn_cvt_pkrtz(q[0], q[1]);
      const f16x2 bb = __builtin_amdgcn_cvt_pkrtz(q[2], q[3]);
      union { f16x4 v; uint2 u; } m;
      m.u.x = __builtin_bit_cast(unsigned, a);
      m.u.y = __builtin_bit_cast(unsigned, bb);
      bQ[tt] = m.v;
    }
  }

  __syncthreads();  // K/V staged

  const int vrow = (ll < 9) ? ll : 8;     // lane-constant PV A-row
  const f32x4 z4 = {0.f, 0.f, 0.f, 0.f};  // persistent zero-C
  f32x4 accO[2] = {};
  // K A-base: lanes hi>=2 (k=8..15, B-side zero) clamp to the hi&1 slot --
  // in-bounds, finite, annihilated by bQ zeros.  [r11 NaN fix]
  const __fp16* akB = Klds + ll * 8 + 4 * (hi & 1);
  const __fp16* avB = Vlds + vrow * 1032 + 4 * hi;   // per-lane V base

  #pragma unroll
  for (int c = 0; c < 8; ++c) {
    #pragma unroll
    for (int ft = 0; ft < 8; ++ft) {
      const f16x4 ak = *(const f16x4*)(akB + c * 1024 + ft * 128);
      const f16x4 av = *(const f16x4*)(avB + c * 128 + ft * 16);
      #pragma unroll
      for (int tt = 0; tt < 2; ++tt) {
        const f32x4 s = __builtin_amdgcn_mfma_f32_16x16x16f16(
            ak, bQ[tt], z4, 0, 0, 0);
        const f16x2 p0 = __builtin_amdgcn_cvt_pkrtz(FEXP2(s[0]), FEXP2(s[1]));
        const f16x2 p1 = __builtin_amdgcn_cvt_pkrtz(FEXP2(s[2]), FEXP2(s[3]));
        union { f16x4 v; uint2 u; } bp;
        bp.u.x = __builtin_bit_cast(unsigned, p0);
        bp.u.y = __builtin_bit_cast(unsigned, p1);
        accO[tt] = __builtin_amdgcn_mfma_f32_16x16x16f16(av, bp.v, accO[tt], 0, 0, 0);
      }
    }
  }

  // ---- epilogue: D row 8 (lane 32+ll, reg 0) = denominator; O out via LDS
  __syncthreads();                 // all waves done with Klds
  short* Olds = KldsS;             // [128][8]
  #pragma unroll
  for (int nt = 0; nt < 2; ++nt) {
    const float sum = __shfl(accO[nt][0], 32 + ll);
    const float inv = 1.f / sum;
    if (hi < 2) {
      const int tl = w * 32 + nt * 16 + ll;
      #pragma unroll
      for (int reg = 0; reg < 4; ++reg)
        Olds[tl * 8 + hi * 4 + reg] = f32_to_bf_bits(accO[nt][reg] * inv);
    }
  }
  __syncthreads();
  if (tid < 128) {
    const short8 ov = *(const short8*)(Olds + tid * 8);
    *(short8*)(hT + ((size_t)b * L_ + tq * 128 + tid) * C_ + d * 8) = ov;
  }
}

// ---------------------------------------------------------------------------
extern "C" void kernel_launch(void* const* d_in, const int* in_sizes, int n_in,
                              void* d_out, int out_size, void* d_ws, size_t ws_size,
                              hipStream_t stream) {
  (void)in_sizes; (void)n_in; (void)out_size; (void)ws_size;
  const float* x      = (const float*)d_in[0];
  const float* gamma  = (const float*)d_in[1];
  const float* beta   = (const float*)d_in[2];
  const float* w_qkv  = (const float*)d_in[3];
  const float* b_qkv  = (const float*)d_in[4];
  const float* w_proj = (const float*)d_in[5];
  const float* b_proj = (const float*)d_in[6];
  float* out = (float*)d_out;
  char* wsb = (char*)d_ws;

  // workspace layout (bytes), ~12 MB
  float* s_buf = (float*)(wsb + 0);                         // 2 KB
  float* t_buf = (float*)(wsb + 2048);                      // 2 KB
  short* wq16  = (short*)(wsb + 4096);                      // 1.5 MB
  short* wpp16 = (short*)(wsb + 4096 + 1572864);            // 0.5 MB
  short* xT    = (short*)(wsb + 4096 + 2097152);            // 2 MB
  short* qkv   = (short*)(wsb + 4096 + 4194304);            // 6 MB
  short* hT    = (short*)(wsb + 4096 + 10485760);           // 2 MB

  hipLaunchKernelGGL(prep_kernel, dim3(768), dim3(256), 0, stream,
                     x, gamma, beta, w_qkv, w_proj, s_buf, t_buf, wq16, wpp16);
  hipLaunchKernelGGL(xt_kernel, dim3(L_ / 64, C_ / 64, B_), dim3(256), 0, stream,
                     x, s_buf, t_buf, xT);
  // qkv[o][t] = wq16 @ xn + b_qkv   (64x64 tiles, 768 blocks = 3/CU)
  hipLaunchKernelGGL((gemm_bt16_kernel<2, 2, true>),
                     dim3(L_ / 64, OC_ / 64, B_), dim3(256), 0, stream,
                     wq16, xT, b_qkv, (const float*)nullptr, (void*)qkv,
                     OC_, L_, C_, (size_t)L_ * C_, (size_t)OC_ * L_, (size_t)0);
  hipLaunchKernelGGL(attn_kernel, dim3(8, HD_, B_), dim3(256), 0, stream,
                     (const __hip_bfloat16*)qkv, hT);
  // out = wpp @ hT^T + b_proj + x   (32x64 tiles, 512 blocks = 2/CU)
  hipLaunchKernelGGL((gemm_bt16_kernel<1, 2, false>),
                     dim3(L_ / 64, C_ / 32, B_), dim3(256), 0, stream,
                     wpp16, hT, b_proj, x, (void*)out,
                     C_, L_, C_, (size_t)L_ * C_, (size_t)C_ * L_, (size_t)C_ * L_);
}